// Round 3
// baseline (303.912 us; speedup 1.0000x reference)
//
#include <hip/hip_runtime.h>

#define N_VOX 100000
#define K_OFF 27
#define M_PAIR 60000
#define NPAIR (K_OFF * M_PAIR)
#define CIN 64
#define COUT 64
#define BN_EPS 1e-5f
#define CNT_STRIDE 16   // one voxel counter per 64B line: kills atomic line contention

#define TILES_PER_WAVE 10
#define WAVES_PER_K (M_PAIR / 16 / TILES_PER_WAVE)   // 375
#define CONV_BLOCKS_X ((WAVES_PER_K + 3) / 4)        // 94

typedef __attribute__((ext_vector_type(8))) short bf16x8;
typedef __attribute__((ext_vector_type(8))) unsigned short u16x8;
typedef __attribute__((ext_vector_type(2))) unsigned int u32x2;
typedef __attribute__((ext_vector_type(4))) float f32x4;

__device__ __forceinline__ unsigned short f32_to_bf16(float f) {
    unsigned int u = __float_as_uint(f);
    u += 0x7FFFu + ((u >> 16) & 1u);
    return (unsigned short)(u >> 16);
}
__device__ __forceinline__ float bf16_lo(unsigned int u) {
    return __uint_as_float(u << 16);
}
__device__ __forceinline__ float bf16_hi(unsigned int u) {
    return __uint_as_float(u & 0xffff0000u);
}
__device__ __forceinline__ float bf16_to_f32(unsigned short b) {
    return __uint_as_float(((unsigned int)b) << 16);
}

// ---------- fused prep: NON-RETURNING hist atomic + feats->bf16 + W^T + BN fold ----------
// The returning rank atomic (72us standalone at ~22.5G atomics/s) is gone; rank
// assignment moved into conv_scatter where it overlaps the GEMM/scatter traffic.
__global__ __launch_bounds__(256) void prep_kernel(
    const int* __restrict__ oix, int* __restrict__ cnt,
    const float* __restrict__ feats, unsigned short* __restrict__ fb,
    const float* __restrict__ W, unsigned short* __restrict__ Wt,
    const float* __restrict__ gamma, const float* __restrict__ beta,
    const float* __restrict__ rmean, const float* __restrict__ rvar,
    float* __restrict__ bnscale, float* __restrict__ bnshift)
{
    const int e = blockIdx.x * blockDim.x + threadIdx.x;
    if (e < NPAIR) atomicAdd(&cnt[oix[e] * CNT_STRIDE], 1);   // no return -> posted
    if (e < (N_VOX * CIN) / 4) {
        const int e4 = e * 4;
        const float4 v = *(const float4*)(feats + e4);
        ushort4 b;
        b.x = f32_to_bf16(v.x);
        b.y = f32_to_bf16(v.y);
        b.z = f32_to_bf16(v.z);
        b.w = f32_to_bf16(v.w);
        *(ushort4*)(fb + e4) = b;
    }
    if (e < K_OFF * CIN * COUT) {
        const int k = e / (CIN * COUT);
        const int r = e % (CIN * COUT);
        Wt[k * CIN * COUT + (r % COUT) * CIN + (r / COUT)] = f32_to_bf16(W[e]);
    }
    if (e < COUT) {
        const float inv = rsqrtf(rvar[e] + BN_EPS);
        const float sc = inv * gamma[e];
        bnscale[e] = sc;
        bnshift[e] = beta[e] - rmean[e] * sc;
    }
}

// ---------- per-block alloc: LDS scan + one global allocator atomic ----------
// Emits seg (segment base), cursor (= seg copy, bumped by conv), cntc (compact count).
__global__ __launch_bounds__(256) void alloc_kernel(
    const int* __restrict__ cnt, int* __restrict__ total, int* __restrict__ seg,
    int* __restrict__ cursor, int* __restrict__ cntc)
{
    __shared__ int part[256];
    __shared__ int bbase;
    const int t = threadIdx.x;
    const int v = blockIdx.x * 256 + t;
    const int c = (v < N_VOX) ? cnt[v * CNT_STRIDE] : 0;
    part[t] = c;
    __syncthreads();
    for (int o = 1; o < 256; o <<= 1) {
        int x = (t >= o) ? part[t - o] : 0;
        __syncthreads();
        part[t] += x;
        __syncthreads();
    }
    if (t == 255) bbase = atomicAdd(total, part[255]);
    __syncthreads();
    if (v < N_VOX) {
        const int base = bbase + (part[t] - c);
        seg[v] = base;
        cursor[v] = base;
        cntc[v] = c;
    }
}

// ---------- phase A: gather-GEMM, pipelined; slot = returning atomic on cursor ----------
// The 1.62M returning atomics hide under conv's ~292MB of HBM traffic (VALUBusy
// was only 16%). Plain (non-NT) stores keep contrib resident in the 256MB MALL
// so gather_bn reads hit L3 instead of HBM.
__global__ __launch_bounds__(256) void conv_scatter_kernel(
    const unsigned short* __restrict__ fb, const unsigned short* __restrict__ Wt,
    const int* __restrict__ in_idx, const int* __restrict__ out_idx,
    int* __restrict__ cursor,
    unsigned short* __restrict__ contrib)
{
    __shared__ alignas(16) unsigned short lds[4][16 * 72];
    const int k = blockIdx.y;
    const int lane = threadIdx.x & 63;
    const int wid = threadIdx.x >> 6;
    const int w = blockIdx.x * 4 + wid;
    if (w >= WAVES_PER_K) return;
    const int col = lane & 15;
    const int quad = lane >> 4;
    unsigned short* L = lds[wid];

    bf16x8 Bf[4][2];
    const short* Wk = (const short*)(Wt + k * CIN * COUT);
#pragma unroll
    for (int t = 0; t < 4; ++t) {
        const short* p = Wk + (t * 16 + col) * CIN + quad * 8;
        Bf[t][0] = *(const bf16x8*)(p);
        Bf[t][1] = *(const bf16x8*)(p + 32);
    }

    int m0 = k * M_PAIR + (w * TILES_PER_WAVE) * 16;
    int slot = 0;
    if (lane < 16) slot = atomicAdd(&cursor[out_idx[m0 + lane]], 1);
    {
        const int rin = in_idx[m0 + col];
        const short* fp = (const short*)fb + (size_t)rin * CIN + quad * 8;
        bf16x8 A0 = *(const bf16x8*)(fp);
        bf16x8 A1 = *(const bf16x8*)(fp + 32);

        for (int it = 0; it < TILES_PER_WAVE; ++it) {
            bf16x8 nA0 = A0, nA1 = A1;
            int nslot = slot;
            if (it + 1 < TILES_PER_WAVE) {
                const int m1 = m0 + 16;
                if (lane < 16)
                    nslot = atomicAdd(&cursor[out_idx[m1 + lane]], 1);
                const int rn = in_idx[m1 + col];
                const short* fn = (const short*)fb + (size_t)rn * CIN + quad * 8;
                nA0 = *(const bf16x8*)(fn);
                nA1 = *(const bf16x8*)(fn + 32);
            }

            f32x4 acc[4];
#pragma unroll
            for (int t = 0; t < 4; ++t) {
                f32x4 z = {0.f, 0.f, 0.f, 0.f};
                acc[t] = __builtin_amdgcn_mfma_f32_16x16x32_bf16(A0, Bf[t][0], z, 0, 0, 0);
                acc[t] = __builtin_amdgcn_mfma_f32_16x16x32_bf16(A1, Bf[t][1], acc[t], 0, 0, 0);
            }
#pragma unroll
            for (int r = 0; r < 4; ++r) {
                const int row = quad * 4 + r;
#pragma unroll
                for (int t = 0; t < 4; ++t)
                    L[row * 72 + t * 16 + col] = f32_to_bf16(acc[t][r]);
            }
#pragma unroll
            for (int itr = 0; itr < 2; ++itr) {
                const int row = itr * 8 + (lane >> 3);
                const int chunk = lane & 7;
                const int pos = __shfl(slot, row, 64);
                const u16x8 v = *(const u16x8*)(L + row * 72 + chunk * 8);
                *(u16x8*)(contrib + (size_t)pos * 64 + chunk * 8) = v;
            }
            A0 = nA0;
            A1 = nA1;
            slot = nslot;
            m0 += 16;
        }
    }
}

// ---------- phase B: streaming segmented sum (u32x2 lanes), fused folded-BN + ReLU ----------
__global__ __launch_bounds__(256) void gather_bn_kernel(
    const unsigned short* __restrict__ contrib, const int* __restrict__ seg,
    const int* __restrict__ cntc,
    const float* __restrict__ bnscale, const float* __restrict__ bnshift,
    float* __restrict__ out)
{
    const int v = blockIdx.x * 4 + (threadIdx.x >> 6);   // one wave per voxel
    if (v >= N_VOX) return;
    const int lane = threadIdx.x & 63;
    const int rg = lane >> 4;          // row group 0..3
    const int cg = lane & 15;          // channel quad 0..15
    const int s = seg[v];
    const int n = cntc[v];

    const u32x2* base = (const u32x2*)(contrib + (size_t)s * 64) + cg;  // row = 16 u32x2
    float a0 = 0.f, a1 = 0.f, a2 = 0.f, a3 = 0.f;
    float b0 = 0.f, b1 = 0.f, b2 = 0.f, b3 = 0.f;
    int j = rg;
    for (; j + 4 < n; j += 8) {        // 2 independent 8B loads in flight
        const u32x2 u = *(base + (size_t)j * 16);
        const u32x2 w = *(base + (size_t)(j + 4) * 16);
        a0 += bf16_lo(u.x); a1 += bf16_hi(u.x);
        a2 += bf16_lo(u.y); a3 += bf16_hi(u.y);
        b0 += bf16_lo(w.x); b1 += bf16_hi(w.x);
        b2 += bf16_lo(w.y); b3 += bf16_hi(w.y);
    }
    for (; j < n; j += 4) {
        const u32x2 u = *(base + (size_t)j * 16);
        a0 += bf16_lo(u.x); a1 += bf16_hi(u.x);
        a2 += bf16_lo(u.y); a3 += bf16_hi(u.y);
    }
    a0 += b0; a1 += b1; a2 += b2; a3 += b3;
    a0 += __shfl_xor(a0, 16, 64); a0 += __shfl_xor(a0, 32, 64);
    a1 += __shfl_xor(a1, 16, 64); a1 += __shfl_xor(a1, 32, 64);
    a2 += __shfl_xor(a2, 16, 64); a2 += __shfl_xor(a2, 32, 64);
    a3 += __shfl_xor(a3, 16, 64); a3 += __shfl_xor(a3, 32, 64);
    if (rg == 0) {
        const int ch = cg * 4;
        float4 r;
        r.x = fmaxf(fmaf(a0, bnscale[ch + 0], bnshift[ch + 0]), 0.f);
        r.y = fmaxf(fmaf(a1, bnscale[ch + 1], bnshift[ch + 1]), 0.f);
        r.z = fmaxf(fmaf(a2, bnscale[ch + 2], bnshift[ch + 2]), 0.f);
        r.w = fmaxf(fmaf(a3, bnscale[ch + 3], bnshift[ch + 3]), 0.f);
        *(float4*)(out + (size_t)v * 64 + ch) = r;
    }
}

// ---------- fallback (atomic path, used if ws too small) ----------
__global__ __launch_bounds__(256) void prep_small_kernel(
    const float* __restrict__ feats, unsigned short* __restrict__ fb,
    float* __restrict__ out, const float* __restrict__ W,
    unsigned short* __restrict__ Wt)
{
    const int e = blockIdx.x * blockDim.x + threadIdx.x;
    if (e < (N_VOX * CIN) / 4) {
        const int e4 = e * 4;
        const float4 v = *(const float4*)(feats + e4);
        ushort4 b;
        b.x = f32_to_bf16(v.x);
        b.y = f32_to_bf16(v.y);
        b.z = f32_to_bf16(v.z);
        b.w = f32_to_bf16(v.w);
        *(ushort4*)(fb + e4) = b;
        *(float4*)(out + e4) = make_float4(0.f, 0.f, 0.f, 0.f);
    }
    if (e < K_OFF * CIN * COUT) {
        const int k = e / (CIN * COUT);
        const int r = e % (CIN * COUT);
        Wt[k * CIN * COUT + (r % COUT) * CIN + (r / COUT)] = f32_to_bf16(W[e]);
    }
}

__global__ __launch_bounds__(256) void conv_atomic_kernel(
    const unsigned short* __restrict__ fb, const unsigned short* __restrict__ Wt,
    const int* __restrict__ in_idx, const int* __restrict__ out_idx,
    float* __restrict__ out)
{
    const int k = blockIdx.y;
    const int lane = threadIdx.x & 63;
    const int wave = blockIdx.x * 4 + (threadIdx.x >> 6);
    const int col = lane & 15;
    const int quad = lane >> 4;
    bf16x8 Bf[4][2];
    const short* Wk = (const short*)(Wt + k * CIN * COUT);
#pragma unroll
    for (int t = 0; t < 4; ++t) {
        const short* p = Wk + (t * 16 + col) * CIN + quad * 8;
        Bf[t][0] = *(const bf16x8*)(p);
        Bf[t][1] = *(const bf16x8*)(p + 32);
    }
    const int base = k * M_PAIR;
    for (int tile = wave; tile < M_PAIR / 16; tile += 128) {
        const int m0 = base + tile * 16;
        const int rin = in_idx[m0 + col];
        const short* fp = (const short*)fb + (size_t)rin * CIN + quad * 8;
        const bf16x8 A0 = *(const bf16x8*)(fp);
        const bf16x8 A1 = *(const bf16x8*)(fp + 32);
        f32x4 acc[4];
#pragma unroll
        for (int t = 0; t < 4; ++t) {
            f32x4 z = {0.f, 0.f, 0.f, 0.f};
            acc[t] = __builtin_amdgcn_mfma_f32_16x16x32_bf16(A0, Bf[t][0], z, 0, 0, 0);
            acc[t] = __builtin_amdgcn_mfma_f32_16x16x32_bf16(A1, Bf[t][1], acc[t], 0, 0, 0);
        }
        int vo[4];
#pragma unroll
        for (int r = 0; r < 4; ++r) vo[r] = out_idx[m0 + quad * 4 + r];
#pragma unroll
        for (int r = 0; r < 4; ++r) {
            float* op = out + (size_t)vo[r] * COUT + col;
#pragma unroll
            for (int t = 0; t < 4; ++t) atomicAdd(op + t * 16, acc[t][r]);
        }
    }
}

__global__ __launch_bounds__(256) void bn_relu_kernel(
    float* __restrict__ out,
    const float* __restrict__ gamma, const float* __restrict__ beta,
    const float* __restrict__ mean, const float* __restrict__ var)
{
    const int e = blockIdx.x * blockDim.x + threadIdx.x;
    if (e >= N_VOX * COUT) return;
    const int c = e & (COUT - 1);
    const float inv = rsqrtf(var[c] + BN_EPS);
    const float y = (out[e] - mean[c]) * (inv * gamma[c]) + beta[c];
    out[e] = fmaxf(y, 0.f);
}

// ---------- host ----------
extern "C" void kernel_launch(void* const* d_in, const int* in_sizes, int n_in,
                              void* d_out, int out_size, void* d_ws, size_t ws_size,
                              hipStream_t stream) {
    const float* feats = (const float*)d_in[0];
    const float* W     = (const float*)d_in[1];
    const float* gamma = (const float*)d_in[2];
    const float* beta  = (const float*)d_in[3];
    const float* rmean = (const float*)d_in[4];
    const float* rvar  = (const float*)d_in[5];
    const int* in_idx  = (const int*)d_in[6];
    const int* out_idx = (const int*)d_in[7];
    float* out = (float*)d_out;

    char* ws = (char*)d_ws;
    size_t off = 0;
    auto alloc = [&](size_t bytes) {
        size_t p = off;
        off = (off + bytes + 255) & ~(size_t)255;
        return p;
    };
    const size_t o_fb   = alloc((size_t)N_VOX * CIN * 2);
    const size_t o_wt   = alloc((size_t)K_OFF * CIN * COUT * 2);
    const size_t o_cnt  = alloc((size_t)N_VOX * CNT_STRIDE * 4 + 4);  // strided cnt + total
    const size_t o_seg  = alloc((size_t)N_VOX * 4);
    const size_t o_cur  = alloc((size_t)N_VOX * 4);
    const size_t o_cntc = alloc((size_t)N_VOX * 4);
    const size_t o_bn   = alloc((size_t)2 * COUT * 4);
    const size_t o_ctr  = alloc((size_t)NPAIR * COUT * 2);
    const bool big = (ws_size >= off);       // constant across calls -> graph-safe

    unsigned short* fb  = (unsigned short*)(ws + o_fb);
    unsigned short* Wt  = (unsigned short*)(ws + o_wt);
    int* cnt            = (int*)(ws + o_cnt);
    int* total          = cnt + (size_t)N_VOX * CNT_STRIDE;  // adjacent
    int* seg            = (int*)(ws + o_seg);
    int* cursor         = (int*)(ws + o_cur);
    int* cntc           = (int*)(ws + o_cntc);
    float* bnscale      = (float*)(ws + o_bn);
    float* bnshift      = bnscale + COUT;
    unsigned short* ctr = (unsigned short*)(ws + o_ctr);

    if (big) {
        hipError_t _e = hipMemsetAsync(cnt, 0, (size_t)N_VOX * CNT_STRIDE * 4 + 4, stream);
        (void)_e;
        prep_kernel<<<(NPAIR + 255) / 256, 256, 0, stream>>>(
            out_idx, cnt, feats, fb, W, Wt,
            gamma, beta, rmean, rvar, bnscale, bnshift);
        alloc_kernel<<<(N_VOX + 255) / 256, 256, 0, stream>>>(cnt, total, seg, cursor, cntc);
        conv_scatter_kernel<<<dim3(CONV_BLOCKS_X, K_OFF), 256, 0, stream>>>(
            fb, Wt, in_idx, out_idx, cursor, ctr);
        gather_bn_kernel<<<(N_VOX + 3) / 4, 256, 0, stream>>>(
            ctr, seg, cntc, bnscale, bnshift, out);
    } else {
        const int ptot = (N_VOX * CIN) / 4;
        prep_small_kernel<<<(ptot + 255) / 256, 256, 0, stream>>>(feats, fb, out, W, Wt);
        conv_atomic_kernel<<<dim3(32, K_OFF), 256, 0, stream>>>(fb, Wt, in_idx, out_idx, out);
        const int total_e = N_VOX * COUT;
        bn_relu_kernel<<<(total_e + 255) / 256, 256, 0, stream>>>(out, gamma, beta, rmean, rvar);
    }
}

// Round 4
// 253.698 us; speedup vs baseline: 1.1979x; 1.1979x over previous
//
#include <hip/hip_runtime.h>

#define N_VOX 100000
#define K_OFF 27
#define M_PAIR 60000
#define NPAIR (K_OFF * M_PAIR)
#define CIN 64
#define COUT 64
#define BN_EPS 1e-5f

// pair->slot assignment via bucketed counting sort (replaces the 1.62M global
// atomics that ran at ~22G/s = 72us):
#define VB_SHIFT 8
#define VB (1 << VB_SHIFT)                       // 256 voxels per bucket
#define NB ((N_VOX + VB - 1) / VB)               // 391 buckets
#define BCAP 5120                                // mean 4147 + 15 sigma
#define PPT 16                                   // pairs per thread, pass A
#define PA_PAIRS (256 * PPT)                     // 4096 per block
#define PA_GRID ((NPAIR + PA_PAIRS - 1) / PA_PAIRS)  // 396

#define TILES_PER_WAVE 10
#define WAVES_PER_K (M_PAIR / 16 / TILES_PER_WAVE)   // 375
#define CONV_BLOCKS_X ((WAVES_PER_K + 3) / 4)        // 94

typedef __attribute__((ext_vector_type(8))) short bf16x8;
typedef __attribute__((ext_vector_type(8))) unsigned short u16x8;
typedef __attribute__((ext_vector_type(2))) unsigned int u32x2;
typedef __attribute__((ext_vector_type(4))) float f32x4;

__device__ __forceinline__ unsigned short f32_to_bf16(float f) {
    unsigned int u = __float_as_uint(f);
    u += 0x7FFFu + ((u >> 16) & 1u);
    return (unsigned short)(u >> 16);
}
__device__ __forceinline__ float bf16_lo(unsigned int u) {
    return __uint_as_float(u << 16);
}
__device__ __forceinline__ float bf16_hi(unsigned int u) {
    return __uint_as_float(u & 0xffff0000u);
}
__device__ __forceinline__ float bf16_to_f32(unsigned short b) {
    return __uint_as_float(((unsigned int)b) << 16);
}

// ---------- pass A: bucket-scatter pair records + fused streaming prep ----------
// Global returning atomics: one per (block,bucket) = ~155K (was 1.62M).
__global__ __launch_bounds__(256) void scatter_pairs_kernel(
    const int* __restrict__ oix,
    unsigned int* __restrict__ recs, int* __restrict__ bucketCount,
    const float* __restrict__ feats, unsigned short* __restrict__ fb,
    const float* __restrict__ W, unsigned short* __restrict__ Wt,
    const float* __restrict__ gamma, const float* __restrict__ beta,
    const float* __restrict__ rmean, const float* __restrict__ rvar,
    float* __restrict__ bnscale, float* __restrict__ bnshift)
{
    __shared__ int lhist[NB];
    __shared__ int gbase[NB];
    const int t = threadIdx.x;
    for (int i = t; i < NB; i += 256) lhist[i] = 0;
    __syncthreads();

    const int base = blockIdx.x * PA_PAIRS;
    int vsave[PPT];
    int lpos[PPT];
#pragma unroll
    for (int i = 0; i < PPT; ++i) {
        const int e = base + i * 256 + t;
        int v = -1, lp = 0;
        if (e < NPAIR) {
            v = oix[e];
            lp = atomicAdd(&lhist[v >> VB_SHIFT], 1);   // LDS returning atomic
        }
        vsave[i] = v;
        lpos[i] = lp;
    }
    __syncthreads();
    for (int i = t; i < NB; i += 256) {
        const int c = lhist[i];
        gbase[i] = c ? atomicAdd(&bucketCount[i], c) : 0;  // 1 global atomic per (block,bucket)
    }
    __syncthreads();
#pragma unroll
    for (int i = 0; i < PPT; ++i) {
        const int v = vsave[i];
        if (v >= 0) {
            const int e = base + i * 256 + t;
            const int b = v >> VB_SHIFT;
            const int idx = gbase[b] + lpos[i];
            if (idx < BCAP)
                recs[(size_t)b * BCAP + idx] =
                    ((unsigned int)e << VB_SHIFT) | (unsigned int)(v & (VB - 1));
        }
    }

    // fused streaming prep (grid-stride)
    const int gid = blockIdx.x * 256 + t;
    const int nt = PA_GRID * 256;
    for (int e4i = gid; e4i < (N_VOX * CIN) / 4; e4i += nt) {
        const int e4 = e4i * 4;
        const float4 v = *(const float4*)(feats + e4);
        ushort4 b;
        b.x = f32_to_bf16(v.x);
        b.y = f32_to_bf16(v.y);
        b.z = f32_to_bf16(v.z);
        b.w = f32_to_bf16(v.w);
        *(ushort4*)(fb + e4) = b;
    }
    for (int e = gid; e < K_OFF * CIN * COUT; e += nt) {
        const int k = e / (CIN * COUT);
        const int r = e % (CIN * COUT);
        Wt[k * CIN * COUT + (r % COUT) * CIN + (r / COUT)] = f32_to_bf16(W[e]);
    }
    if (gid < COUT) {
        const float inv = rsqrtf(rvar[gid] + BN_EPS);
        const float sc = inv * gamma[gid];
        bnscale[gid] = sc;
        bnshift[gid] = beta[gid] - rmean[gid] * sc;
    }
}

// ---------- pass B: per-bucket LDS rank + compact counts ----------
__global__ __launch_bounds__(256) void rank_kernel(
    const unsigned int* __restrict__ recs, const int* __restrict__ bucketCount,
    int* __restrict__ rank, int* __restrict__ cntc)
{
    __shared__ int hist[VB];
    const int b = blockIdx.x;
    const int t = threadIdx.x;
    hist[t] = 0;
    __syncthreads();
    int bc = bucketCount[b];
    if (bc > BCAP) bc = BCAP;
    const unsigned int* r = recs + (size_t)b * BCAP;
    for (int i = t; i < bc; i += 256) {
        const unsigned int rec = r[i];
        const int vl = rec & (VB - 1);
        const int pid = rec >> VB_SHIFT;
        rank[pid] = atomicAdd(&hist[vl], 1);   // LDS returning atomic
    }
    __syncthreads();
    const int v = b * VB + t;
    if (v < N_VOX) cntc[v] = hist[t];
}

// ---------- alloc: LDS scan over compact counts + one global allocator atomic ----------
__global__ __launch_bounds__(256) void alloc_kernel(
    const int* __restrict__ cntc, int* __restrict__ total, int* __restrict__ seg)
{
    __shared__ int part[256];
    __shared__ int bbase;
    const int t = threadIdx.x;
    const int v = blockIdx.x * 256 + t;
    const int c = (v < N_VOX) ? cntc[v] : 0;
    part[t] = c;
    __syncthreads();
    for (int o = 1; o < 256; o <<= 1) {
        int x = (t >= o) ? part[t - o] : 0;
        __syncthreads();
        part[t] += x;
        __syncthreads();
    }
    if (t == 255) bbase = atomicAdd(total, part[255]);
    __syncthreads();
    if (v < N_VOX) seg[v] = bbase + (part[t] - c);
}

// ---------- phase A: gather-GEMM, pipelined, NT sorted-slot stores (round-2 form) ----------
__global__ __launch_bounds__(256) void conv_scatter_kernel(
    const unsigned short* __restrict__ fb, const unsigned short* __restrict__ Wt,
    const int* __restrict__ in_idx, const int* __restrict__ out_idx,
    const int* __restrict__ rank, const int* __restrict__ seg,
    unsigned short* __restrict__ contrib)
{
    __shared__ alignas(16) unsigned short lds[4][16 * 72];
    const int k = blockIdx.y;
    const int lane = threadIdx.x & 63;
    const int wid = threadIdx.x >> 6;
    const int w = blockIdx.x * 4 + wid;
    if (w >= WAVES_PER_K) return;
    const int col = lane & 15;
    const int quad = lane >> 4;
    unsigned short* L = lds[wid];

    bf16x8 Bf[4][2];
    const short* Wk = (const short*)(Wt + k * CIN * COUT);
#pragma unroll
    for (int t = 0; t < 4; ++t) {
        const short* p = Wk + (t * 16 + col) * CIN + quad * 8;
        Bf[t][0] = *(const bf16x8*)(p);
        Bf[t][1] = *(const bf16x8*)(p + 32);
    }

    int m0 = k * M_PAIR + (w * TILES_PER_WAVE) * 16;
    int slot = 0;
    if (lane < 16) slot = seg[out_idx[m0 + lane]] + rank[m0 + lane];
    {
        const int rin = in_idx[m0 + col];
        const short* fp = (const short*)fb + (size_t)rin * CIN + quad * 8;
        bf16x8 A0 = *(const bf16x8*)(fp);
        bf16x8 A1 = *(const bf16x8*)(fp + 32);

        for (int it = 0; it < TILES_PER_WAVE; ++it) {
            bf16x8 nA0 = A0, nA1 = A1;
            int nslot = slot;
            if (it + 1 < TILES_PER_WAVE) {
                const int m1 = m0 + 16;
                if (lane < 16)
                    nslot = seg[out_idx[m1 + lane]] + rank[m1 + lane];
                const int rn = in_idx[m1 + col];
                const short* fn = (const short*)fb + (size_t)rn * CIN + quad * 8;
                nA0 = *(const bf16x8*)(fn);
                nA1 = *(const bf16x8*)(fn + 32);
            }

            f32x4 acc[4];
#pragma unroll
            for (int t = 0; t < 4; ++t) {
                f32x4 z = {0.f, 0.f, 0.f, 0.f};
                acc[t] = __builtin_amdgcn_mfma_f32_16x16x32_bf16(A0, Bf[t][0], z, 0, 0, 0);
                acc[t] = __builtin_amdgcn_mfma_f32_16x16x32_bf16(A1, Bf[t][1], acc[t], 0, 0, 0);
            }
#pragma unroll
            for (int r = 0; r < 4; ++r) {
                const int row = quad * 4 + r;
#pragma unroll
                for (int t = 0; t < 4; ++t)
                    L[row * 72 + t * 16 + col] = f32_to_bf16(acc[t][r]);
            }
#pragma unroll
            for (int itr = 0; itr < 2; ++itr) {
                const int row = itr * 8 + (lane >> 3);
                const int chunk = lane & 7;
                const int pos = __shfl(slot, row, 64);
                const u16x8 v = *(const u16x8*)(L + row * 72 + chunk * 8);
                __builtin_nontemporal_store(
                    v, (u16x8*)(contrib + (size_t)pos * 64 + chunk * 8));
            }
            A0 = nA0;
            A1 = nA1;
            slot = nslot;
            m0 += 16;
        }
    }
}

// ---------- phase B: streaming segmented sum (u32x2 lanes), fused folded-BN + ReLU ----------
__global__ __launch_bounds__(256) void gather_bn_kernel(
    const unsigned short* __restrict__ contrib, const int* __restrict__ seg,
    const int* __restrict__ cntc,
    const float* __restrict__ bnscale, const float* __restrict__ bnshift,
    float* __restrict__ out)
{
    const int v = blockIdx.x * 4 + (threadIdx.x >> 6);   // one wave per voxel
    if (v >= N_VOX) return;
    const int lane = threadIdx.x & 63;
    const int rg = lane >> 4;          // row group 0..3
    const int cg = lane & 15;          // channel quad 0..15
    const int s = seg[v];
    const int n = cntc[v];

    const u32x2* base = (const u32x2*)(contrib + (size_t)s * 64) + cg;  // row = 16 u32x2
    float a0 = 0.f, a1 = 0.f, a2 = 0.f, a3 = 0.f;
    float b0 = 0.f, b1 = 0.f, b2 = 0.f, b3 = 0.f;
    int j = rg;
    for (; j + 4 < n; j += 8) {        // 2 independent 8B loads in flight
        const u32x2 u = __builtin_nontemporal_load(base + (size_t)j * 16);
        const u32x2 w = __builtin_nontemporal_load(base + (size_t)(j + 4) * 16);
        a0 += bf16_lo(u.x); a1 += bf16_hi(u.x);
        a2 += bf16_lo(u.y); a3 += bf16_hi(u.y);
        b0 += bf16_lo(w.x); b1 += bf16_hi(w.x);
        b2 += bf16_lo(w.y); b3 += bf16_hi(w.y);
    }
    for (; j < n; j += 4) {
        const u32x2 u = __builtin_nontemporal_load(base + (size_t)j * 16);
        a0 += bf16_lo(u.x); a1 += bf16_hi(u.x);
        a2 += bf16_lo(u.y); a3 += bf16_hi(u.y);
    }
    a0 += b0; a1 += b1; a2 += b2; a3 += b3;
    a0 += __shfl_xor(a0, 16, 64); a0 += __shfl_xor(a0, 32, 64);
    a1 += __shfl_xor(a1, 16, 64); a1 += __shfl_xor(a1, 32, 64);
    a2 += __shfl_xor(a2, 16, 64); a2 += __shfl_xor(a2, 32, 64);
    a3 += __shfl_xor(a3, 16, 64); a3 += __shfl_xor(a3, 32, 64);
    if (rg == 0) {
        const int ch = cg * 4;
        float4 r;
        r.x = fmaxf(fmaf(a0, bnscale[ch + 0], bnshift[ch + 0]), 0.f);
        r.y = fmaxf(fmaf(a1, bnscale[ch + 1], bnshift[ch + 1]), 0.f);
        r.z = fmaxf(fmaf(a2, bnscale[ch + 2], bnshift[ch + 2]), 0.f);
        r.w = fmaxf(fmaf(a3, bnscale[ch + 3], bnshift[ch + 3]), 0.f);
        *(float4*)(out + (size_t)v * 64 + ch) = r;
    }
}

// ---------- fallback (atomic path, used if ws too small) ----------
__global__ __launch_bounds__(256) void prep_small_kernel(
    const float* __restrict__ feats, unsigned short* __restrict__ fb,
    float* __restrict__ out, const float* __restrict__ W,
    unsigned short* __restrict__ Wt)
{
    const int e = blockIdx.x * blockDim.x + threadIdx.x;
    if (e < (N_VOX * CIN) / 4) {
        const int e4 = e * 4;
        const float4 v = *(const float4*)(feats + e4);
        ushort4 b;
        b.x = f32_to_bf16(v.x);
        b.y = f32_to_bf16(v.y);
        b.z = f32_to_bf16(v.z);
        b.w = f32_to_bf16(v.w);
        *(ushort4*)(fb + e4) = b;
        *(float4*)(out + e4) = make_float4(0.f, 0.f, 0.f, 0.f);
    }
    if (e < K_OFF * CIN * COUT) {
        const int k = e / (CIN * COUT);
        const int r = e % (CIN * COUT);
        Wt[k * CIN * COUT + (r % COUT) * CIN + (r / COUT)] = f32_to_bf16(W[e]);
    }
}

__global__ __launch_bounds__(256) void conv_atomic_kernel(
    const unsigned short* __restrict__ fb, const unsigned short* __restrict__ Wt,
    const int* __restrict__ in_idx, const int* __restrict__ out_idx,
    float* __restrict__ out)
{
    const int k = blockIdx.y;
    const int lane = threadIdx.x & 63;
    const int wave = blockIdx.x * 4 + (threadIdx.x >> 6);
    const int col = lane & 15;
    const int quad = lane >> 4;
    bf16x8 Bf[4][2];
    const short* Wk = (const short*)(Wt + k * CIN * COUT);
#pragma unroll
    for (int t = 0; t < 4; ++t) {
        const short* p = Wk + (t * 16 + col) * CIN + quad * 8;
        Bf[t][0] = *(const bf16x8*)(p);
        Bf[t][1] = *(const bf16x8*)(p + 32);
    }
    const int base = k * M_PAIR;
    for (int tile = wave; tile < M_PAIR / 16; tile += 128) {
        const int m0 = base + tile * 16;
        const int rin = in_idx[m0 + col];
        const short* fp = (const short*)fb + (size_t)rin * CIN + quad * 8;
        const bf16x8 A0 = *(const bf16x8*)(fp);
        const bf16x8 A1 = *(const bf16x8*)(fp + 32);
        f32x4 acc[4];
#pragma unroll
        for (int t = 0; t < 4; ++t) {
            f32x4 z = {0.f, 0.f, 0.f, 0.f};
            acc[t] = __builtin_amdgcn_mfma_f32_16x16x32_bf16(A0, Bf[t][0], z, 0, 0, 0);
            acc[t] = __builtin_amdgcn_mfma_f32_16x16x32_bf16(A1, Bf[t][1], acc[t], 0, 0, 0);
        }
        int vo[4];
#pragma unroll
        for (int r = 0; r < 4; ++r) vo[r] = out_idx[m0 + quad * 4 + r];
#pragma unroll
        for (int r = 0; r < 4; ++r) {
            float* op = out + (size_t)vo[r] * COUT + col;
#pragma unroll
            for (int t = 0; t < 4; ++t) atomicAdd(op + t * 16, acc[t][r]);
        }
    }
}

__global__ __launch_bounds__(256) void bn_relu_kernel(
    float* __restrict__ out,
    const float* __restrict__ gamma, const float* __restrict__ beta,
    const float* __restrict__ mean, const float* __restrict__ var)
{
    const int e = blockIdx.x * blockDim.x + threadIdx.x;
    if (e >= N_VOX * COUT) return;
    const int c = e & (COUT - 1);
    const float inv = rsqrtf(var[c] + BN_EPS);
    const float y = (out[e] - mean[c]) * (inv * gamma[c]) + beta[c];
    out[e] = fmaxf(y, 0.f);
}

// ---------- host ----------
extern "C" void kernel_launch(void* const* d_in, const int* in_sizes, int n_in,
                              void* d_out, int out_size, void* d_ws, size_t ws_size,
                              hipStream_t stream) {
    const float* feats = (const float*)d_in[0];
    const float* W     = (const float*)d_in[1];
    const float* gamma = (const float*)d_in[2];
    const float* beta  = (const float*)d_in[3];
    const float* rmean = (const float*)d_in[4];
    const float* rvar  = (const float*)d_in[5];
    const int* in_idx  = (const int*)d_in[6];
    const int* out_idx = (const int*)d_in[7];
    float* out = (float*)d_out;

    char* ws = (char*)d_ws;
    size_t off = 0;
    auto alloc = [&](size_t bytes) {
        size_t p = off;
        off = (off + bytes + 255) & ~(size_t)255;
        return p;
    };
    const size_t o_fb   = alloc((size_t)N_VOX * CIN * 2);
    const size_t o_wt   = alloc((size_t)K_OFF * CIN * COUT * 2);
    const size_t o_bc   = alloc((size_t)NB * 4 + 4);          // bucketCount + total
    const size_t o_recs = alloc((size_t)NB * BCAP * 4);
    const size_t o_seg  = alloc((size_t)N_VOX * 4);
    const size_t o_cntc = alloc((size_t)N_VOX * 4);
    const size_t o_bn   = alloc((size_t)2 * COUT * 4);
    const size_t o_rank = alloc((size_t)NPAIR * 4);
    const size_t o_ctr  = alloc((size_t)NPAIR * COUT * 2);
    const bool big = (ws_size >= off);       // constant across calls -> graph-safe

    unsigned short* fb  = (unsigned short*)(ws + o_fb);
    unsigned short* Wt  = (unsigned short*)(ws + o_wt);
    int* bucketCount    = (int*)(ws + o_bc);
    int* total          = bucketCount + NB;
    unsigned int* recs  = (unsigned int*)(ws + o_recs);
    int* seg            = (int*)(ws + o_seg);
    int* cntc           = (int*)(ws + o_cntc);
    float* bnscale      = (float*)(ws + o_bn);
    float* bnshift      = bnscale + COUT;
    int* rank           = (int*)(ws + o_rank);
    unsigned short* ctr = (unsigned short*)(ws + o_ctr);

    if (big) {
        hipError_t _e = hipMemsetAsync(bucketCount, 0, (size_t)NB * 4 + 4, stream);
        (void)_e;
        scatter_pairs_kernel<<<PA_GRID, 256, 0, stream>>>(
            out_idx, recs, bucketCount, feats, fb, W, Wt,
            gamma, beta, rmean, rvar, bnscale, bnshift);
        rank_kernel<<<NB, 256, 0, stream>>>(recs, bucketCount, rank, cntc);
        alloc_kernel<<<(N_VOX + 255) / 256, 256, 0, stream>>>(cntc, total, seg);
        conv_scatter_kernel<<<dim3(CONV_BLOCKS_X, K_OFF), 256, 0, stream>>>(
            fb, Wt, in_idx, out_idx, rank, seg, ctr);
        gather_bn_kernel<<<(N_VOX + 3) / 4, 256, 0, stream>>>(
            ctr, seg, cntc, bnscale, bnshift, out);
    } else {
        const int ptot = (N_VOX * CIN) / 4;
        prep_small_kernel<<<(ptot + 255) / 256, 256, 0, stream>>>(feats, fb, out, W, Wt);
        conv_atomic_kernel<<<dim3(32, K_OFF), 256, 0, stream>>>(fb, Wt, in_idx, out_idx, out);
        const int total_e = N_VOX * COUT;
        bn_relu_kernel<<<(total_e + 255) / 256, 256, 0, stream>>>(out, gamma, beta, rmean, rvar);
    }
}